// Round 11
// baseline (1753.450 us; speedup 1.0000x reference)
//
#include <hip/hip_runtime.h>
#include <hip/hip_bf16.h>
#include <stdint.h>

typedef unsigned short u16;
typedef __bf16 bf16x8 __attribute__((ext_vector_type(8)));
typedef u16 u16x8 __attribute__((ext_vector_type(8)));
typedef float f32x4 __attribute__((ext_vector_type(4)));
typedef float f32x16 __attribute__((ext_vector_type(16)));
typedef uint32_t u32x4 __attribute__((ext_vector_type(4)));

#define DEV __device__ __forceinline__
#define SBAR() asm volatile("s_barrier" ::: "memory")
#define SCHEDB() __builtin_amdgcn_sched_barrier(0)
#define LGKM0() do { asm volatile("s_waitcnt lgkmcnt(0)" ::: "memory"); SCHEDB(); } while (0)

DEV u16 f2bf(float f) {
  uint32_t u = __builtin_bit_cast(uint32_t, f);
  return (u16)((u + 0x7FFFu + ((u >> 16) & 1u)) >> 16);
}
DEV float bf2f(u16 h) { return __builtin_bit_cast(float, (uint32_t)h << 16); }

DEV void gload_lds16(const void* g, void* l) {
  __builtin_amdgcn_global_load_lds((const __attribute__((address_space(1))) uint32_t*)g,
                                   (__attribute__((address_space(3))) uint32_t*)l, 16, 0, 0);
}

DEV uint32_t cvtpk(float lo, float hi) {
  uint32_t r;
  asm("v_cvt_pk_bf16_f32 %0, %1, %2" : "=v"(r) : "v"(lo), "v"(hi));
  return r;
}
DEV void plswap(uint32_t& a, uint32_t& b) {
  asm("v_permlane32_swap_b32 %0, %1" : "+v"(a), "+v"(b));
}

// ---------------- elementwise f32 -> bf16 cast ----------------
__global__ void cvt_bf16(const float* __restrict__ in, u16* __restrict__ out, int n) {
  int i = (blockIdx.x * 256 + threadIdx.x) * 8;
  if (i >= n) return;
  const float4* p = reinterpret_cast<const float4*>(in + i);
  float4 a = p[0], b = p[1];
  u16x8 o;
  o[0] = f2bf(a.x); o[1] = f2bf(a.y); o[2] = f2bf(a.z); o[3] = f2bf(a.w);
  o[4] = f2bf(b.x); o[5] = f2bf(b.y); o[6] = f2bf(b.z); o[7] = f2bf(b.w);
  *reinterpret_cast<u16x8*>(out + i) = o;
}

// ---------------- RoPE cos/sin table (S=2048, 64 pairs) ----------------
__global__ void rope_table(float* __restrict__ ct, float* __restrict__ st) {
  int i = blockIdx.x * 256 + threadIdx.x;
  int s = i >> 6, d = i & 63;
  float invf = powf(10000.0f, -(float)d * (1.0f / 64.0f));
  float ang = (float)s * invf;
  ct[i] = cosf(ang);
  st[i] = sinf(ang);
}

// ---------------- RoPE applied in-place on bf16 qkv ----------------
__global__ void rope_apply(u16* __restrict__ qkv, const float* __restrict__ ct, const float* __restrict__ st) {
  int idx = blockIdx.x * 256 + threadIdx.x;
  int grp = idx & 7;
  int head = (idx >> 3) % 40;
  int row = idx / 320;
  int s = row & 2047;
  size_t f0 = head < 32 ? (size_t)head * 128 : (size_t)4096 + (size_t)(head - 32) * 128;
  u16* p = qkv + (size_t)row * 6144 + f0 + grp * 8;
  u16x8 a = *reinterpret_cast<const u16x8*>(p);
  u16x8 b = *reinterpret_cast<const u16x8*>(p + 64);
  const float4* cp = reinterpret_cast<const float4*>(ct + s * 64 + grp * 8);
  const float4* sp = reinterpret_cast<const float4*>(st + s * 64 + grp * 8);
  float4 c0 = cp[0], c1 = cp[1], s0 = sp[0], s1 = sp[1];
  float cc[8] = {c0.x, c0.y, c0.z, c0.w, c1.x, c1.y, c1.z, c1.w};
  float ss[8] = {s0.x, s0.y, s0.z, s0.w, s1.x, s1.y, s1.z, s1.w};
  u16x8 o1, o2;
#pragma unroll
  for (int i = 0; i < 8; i++) {
    float x1 = bf2f(a[i]), x2 = bf2f(b[i]);
    o1[i] = f2bf(x1 * cc[i] - x2 * ss[i]);
    o2[i] = f2bf(x2 * cc[i] + x1 * ss[i]);
  }
  *reinterpret_cast<u16x8*>(p) = o1;
  *reinterpret_cast<u16x8*>(p + 64) = o2;
}

// ---------------- V^T tile image prep ----------------
__global__ void prep_vt(const u16* __restrict__ qkv, u16* __restrict__ vtg) {
  int id = blockIdx.x;  // (b*8+kvh)*32 + j
  int j = id & 31, kvh = (id >> 5) & 7, b = id >> 8;
  const int tid = threadIdx.x;
  const size_t rowB = (size_t)b * 2048;
  u16* img = vtg + (size_t)id * 8192;
#pragma unroll
  for (int p = 0; p < 4; p++) {
    int lin = p * 256 + tid;
    int d = lin >> 3, c = lin & 7;
    const u16* src = qkv + (rowB + j * 64 + c * 8) * 6144 + 5120 + kvh * 128 + d;
    u16x8 v;
#pragma unroll
    for (int i = 0; i < 8; i++) v[i] = src[(size_t)i * 6144];
    *reinterpret_cast<u16x8*>(img + d * 64 + ((c ^ (d & 7)) << 3)) = v;
  }
}

// ---------------- GEMM epilogue store helpers ----------------
DEV void store_c(float* C, size_t idx, float v) { C[idx] = v; }
DEV void store_c(u16* C, size_t idx, float v) { C[idx] = f2bf(v); }

// ---------------- 256x256 GEMM, read-pipelined 4-phase (reads issue under MFMA) ----------------
// LDS 128 KiB -> only ONE 512-thread block/CU can ever be resident, so declare
// __launch_bounds__(512, 1): real occupancy unchanged, VGPR cap 128 -> 256
// (round-10 spill fix; schedule needs ~250 live VGPRs).
// Per tile t: P1{lgkm0; issue fB1; Q00} P2{stage B0(t+2); lgkm0; issue fAH; Q01}
//             P3{stage B1(t+2); lgkm0; Q11; vmcnt(4); SBAR}
//             P4{stage A0,A1(t+2); issue fAL(t+1)+fB0next(t+1); Q10}  (no barrier)
template <typename OutT>
__global__ __launch_bounds__(512, 1) void gemm256(const u16* __restrict__ A, const u16* __restrict__ B,
                                                  OutT* __restrict__ C, int M, int N, int K, int ldc) {
  __shared__ __align__(16) u16 lds[65536];  // 128 KiB
  char* LB = (char*)lds;
  const int tid = threadIdx.x;
  const int w = tid >> 6, lane = tid & 63;
  const int l15 = lane & 15, l4 = lane >> 4;
  const int wm = w >> 2, wn = w & 3;

  int nwg = gridDim.x;
  int q = nwg >> 3, rr = nwg & 7;
  int xcd = blockIdx.x & 7, idx = blockIdx.x >> 3;
  int sw = (xcd < rr ? xcd * (q + 1) : rr * (q + 1) + (xcd - rr) * q) + idx;
  int gxn = N >> 8;
  int by = sw / gxn, bx = sw - by * gxn;
  const int row0 = by << 8, col0 = bx << 8;
  const int NT = K >> 6;  // even (K=4096 -> 64)

  const int srow = w * 8 + (lane >> 3);
  const int sc16 = (lane & 7) ^ ((lane >> 3) & 7);
  const u16* gA = A + (size_t)(row0 + srow) * K + sc16 * 8;
  const u16* gB = B + (size_t)(col0 + srow) * K + sc16 * 8;

  const int fl = (l15 & 7) << 4;
  const int aoff = (wm * 128 + l15) * 128 + l4 * 16;
  const int boff = (wn * 64 + l15) * 128 + l4 * 16;

  f32x4 acc[8][4] = {};
  bf16x8 fAL[4][2], fAH[4][2], fB1[2][2], fB0e[2][2], fB0o[2][2];

#define STAGE_A(kt, h, base)                                                      \
  {                                                                               \
    const u16* g_ = gA + (size_t)((h)*128) * K + (size_t)(kt)*64;                 \
    gload_lds16(g_, (base) + (h)*16384 + w * 1024);                               \
    gload_lds16(g_ + (size_t)64 * K, (base) + (h)*16384 + 8192 + w * 1024);       \
  }
#define STAGE_B(kt, h, base)                                                      \
  {                                                                               \
    const u16* g_ = gB + (size_t)((h)*128) * K + (size_t)(kt)*64;                 \
    gload_lds16(g_, (base) + (h)*16384 + w * 1024);                               \
    gload_lds16(g_ + (size_t)64 * K, (base) + (h)*16384 + 8192 + w * 1024);       \
  }
#define READ_AL(base)                                                             \
  _Pragma("unroll") for (int mf = 0; mf < 4; mf++)                                \
    _Pragma("unroll") for (int kk = 0; kk < 2; kk++)                              \
      fAL[mf][kk] = *(const bf16x8*)((base) + ((aoff + mf * 2048 + kk * 64) ^ fl));
#define READ_AH(base)                                                             \
  _Pragma("unroll") for (int mf = 0; mf < 4; mf++)                                \
    _Pragma("unroll") for (int kk = 0; kk < 2; kk++)                              \
      fAH[mf][kk] = *(const bf16x8*)((base) + ((aoff + (mf + 4) * 2048 + kk * 64) ^ fl));
#define READ_B(FB, base, nh)                                                      \
  _Pragma("unroll") for (int nf = 0; nf < 2; nf++)                                \
    _Pragma("unroll") for (int kk = 0; kk < 2; kk++)                              \
      FB[nf][kk] = *(const bf16x8*)((base) + ((boff + (nf + 2 * (nh)) * 2048 + kk * 64) ^ fl));
#define MFMA_Q(FA, FB, MH, NH)                                                    \
  _Pragma("unroll") for (int kk = 0; kk < 2; kk++) {                              \
    _Pragma("unroll") for (int mf = 0; mf < 4; mf++) {                            \
      _Pragma("unroll") for (int nf = 0; nf < 2; nf++) {                          \
        acc[(MH)*4 + mf][(NH)*2 + nf] = __builtin_amdgcn_mfma_f32_16x16x32_bf16(  \
            FA[mf][kk], FB[nf][kk], acc[(MH)*4 + mf][(NH)*2 + nf], 0, 0, 0);      \
      }                                                                           \
    }                                                                             \
  }

  // prologue: tile0 {A0,A1,B0,B1} -> buf0; tile1 staged IN ORDER {B0,B1,A0,A1} -> buf1
  STAGE_A(0, 0, LB);
  STAGE_A(0, 1, LB);
  STAGE_B(0, 0, LB + 65536);
  STAGE_B(0, 1, LB + 65536);
  STAGE_B(1, 0, LB + 98304);
  STAGE_B(1, 1, LB + 98304);
  STAGE_A(1, 0, LB + 32768);
  STAGE_A(1, 1, LB + 32768);
  asm volatile("s_waitcnt vmcnt(8)" ::: "memory");  // tile0 resident; tile1's 8 in flight
  SBAR();
  // prime reads for tile0 P1
  READ_AL(LB);
  READ_B(fB0e, LB + 65536, 0);
  SCHEDB();

#define TILE_BODY(t, AC, BC, AN, BN, FB0C, FB0N)                                  \
  {                                                                               \
    /* P1 */                                                                      \
    LGKM0();                                                                      \
    READ_B(fB1, BC, 1);                                                           \
    SCHEDB();                                                                     \
    __builtin_amdgcn_s_setprio(1);                                                \
    MFMA_Q(fAL, FB0C, 0, 0);                                                      \
    __builtin_amdgcn_s_setprio(0);                                                \
    SBAR();                                                                       \
    /* P2 */                                                                      \
    if ((t) + 2 < NT) STAGE_B((t) + 2, 0, BC);                                    \
    LGKM0();                                                                      \
    READ_AH(AC);                                                                  \
    SCHEDB();                                                                     \
    __builtin_amdgcn_s_setprio(1);                                                \
    MFMA_Q(fAL, fB1, 0, 1);                                                       \
    __builtin_amdgcn_s_setprio(0);                                                \
    SBAR();                                                                       \
    /* P3 */                                                                      \
    if ((t) + 2 < NT) STAGE_B((t) + 2, 1, BC);                                    \
    LGKM0();                                                                      \
    __builtin_amdgcn_s_setprio(1);                                                \
    MFMA_Q(fAH, fB1, 1, 1);                                                       \
    __builtin_amdgcn_s_setprio(0);                                                \
    if ((t) + 2 < NT) {                                                           \
      asm volatile("s_waitcnt vmcnt(4)" ::: "memory");                            \
    } else if ((t) + 1 < NT) {                                                    \
      asm volatile("s_waitcnt vmcnt(0)" ::: "memory");                            \
    }                                                                             \
    SBAR();                                                                       \
    /* P4 */                                                                      \
    if ((t) + 2 < NT) {                                                           \
      STAGE_A((t) + 2, 0, AC);                                                    \
      STAGE_A((t) + 2, 1, AC);                                                    \
    }                                                                             \
    if ((t) + 1 < NT) {                                                           \
      READ_AL(AN);                                                                \
      READ_B(FB0N, BN, 0);                                                        \
    }                                                                             \
    SCHEDB();                                                                     \
    __builtin_amdgcn_s_setprio(1);                                                \
    MFMA_Q(fAH, FB0C, 1, 0);                                                      \
    __builtin_amdgcn_s_setprio(0);                                                \
  }

  for (int t = 0; t < NT; t += 2) {
    TILE_BODY(t, LB, LB + 65536, LB + 32768, LB + 98304, fB0e, fB0o);
    TILE_BODY(t + 1, LB + 32768, LB + 98304, LB, LB + 65536, fB0o, fB0e);
  }

#pragma unroll
  for (int mf = 0; mf < 8; mf++)
#pragma unroll
    for (int nf = 0; nf < 4; nf++)
#pragma unroll
      for (int r = 0; r < 4; r++) {
        size_t row = (size_t)row0 + wm * 128 + mf * 16 + l4 * 4 + r;
        size_t col = (size_t)col0 + wn * 64 + nf * 16 + l15;
        store_c(C, row * (size_t)ldc + col, acc[mf][nf][r]);
      }
#undef STAGE_A
#undef STAGE_B
#undef READ_AL
#undef READ_AH
#undef READ_B
#undef MFMA_Q
#undef TILE_BODY
}

// ---------------- 256x128 GEMM, 3-phase cross-barrier (gemm1 K/V columns; round-9 proven) ----------------
__global__ __launch_bounds__(512, 2) void gemm_bn128(const u16* __restrict__ A, const u16* __restrict__ B,
                                                     u16* __restrict__ C, int M, int N, int K, int ldc) {
  __shared__ __align__(16) u16 lds[49152];  // 96 KiB
  char* LB = (char*)lds;
  const int tid = threadIdx.x;
  const int w = tid >> 6, lane = tid & 63;
  const int l15 = lane & 15, l4 = lane >> 4;
  const int wm = w >> 2, wn = w & 3;

  int nwg = gridDim.x;
  int q = nwg >> 3, rr = nwg & 7;
  int xcd = blockIdx.x & 7, idx = blockIdx.x >> 3;
  int sw = (xcd < rr ? xcd * (q + 1) : rr * (q + 1) + (xcd - rr) * q) + idx;
  int gxn = N >> 7;
  int by = sw / gxn, bx = sw - by * gxn;
  const int row0 = by << 8, col0 = bx << 7;
  const int NT = K >> 6;

  const int srow = w * 8 + (lane >> 3);
  const int sc16 = (lane & 7) ^ ((lane >> 3) & 7);
  const u16* gA = A + (size_t)(row0 + srow) * K + sc16 * 8;
  const u16* gB = B + (size_t)(col0 + srow) * K + sc16 * 8;

  const int fl = (l15 & 7) << 4;
  const int aoff = (wm * 128 + l15) * 128 + l4 * 16;
  const int boff = (wn * 32 + l15) * 128 + l4 * 16;

  f32x4 acc[8][2] = {};
  bf16x8 fA[4][2], fB[2][2];

#define STAGE_A(kt, h, base)                                                      \
  {                                                                               \
    const u16* g_ = gA + (size_t)((h)*128) * K + (size_t)(kt)*64;                 \
    gload_lds16(g_, (base) + (h)*16384 + w * 1024);                               \
    gload_lds16(g_ + (size_t)64 * K, (base) + (h)*16384 + 8192 + w * 1024);       \
  }
#define STAGE_B(kt, base)                                                         \
  {                                                                               \
    const u16* g_ = gB + (size_t)(kt)*64;                                         \
    gload_lds16(g_, (base) + w * 1024);                                           \
    gload_lds16(g_ + (size_t)64 * K, (base) + 8192 + w * 1024);                   \
  }

  STAGE_A(0, 0, LB);
  STAGE_A(0, 1, LB);
  STAGE_B(0, LB + 65536);
  STAGE_A(1, 0, LB + 32768);
  STAGE_B(1, LB + 65536 + 16384);
  asm volatile("s_waitcnt vmcnt(4)" ::: "memory");
  SBAR();

  for (int t = 0; t < NT; ++t) {
    char* ac = LB + (t & 1) * 32768;
    char* bc = LB + 65536 + (t & 1) * 16384;
    char* an = LB + ((t + 1) & 1) * 32768;

    // ---- P1 ----
#pragma unroll
    for (int mf = 0; mf < 4; mf++)
#pragma unroll
      for (int kk = 0; kk < 2; kk++)
        fA[mf][kk] = *(const bf16x8*)(ac + ((aoff + mf * 2048 + kk * 64) ^ fl));
#pragma unroll
    for (int nf = 0; nf < 2; nf++)
#pragma unroll
      for (int kk = 0; kk < 2; kk++)
        fB[nf][kk] = *(const bf16x8*)(bc + ((boff + nf * 2048 + kk * 64) ^ fl));
    if (t + 1 < NT) STAGE_A(t + 1, 1, an);
    SBAR();
    LGKM0();
    __builtin_amdgcn_s_setprio(1);
#pragma unroll
    for (int kk = 0; kk < 2; kk++)
#pragma unroll
      for (int mf = 0; mf < 4; mf++)
#pragma unroll
        for (int nf = 0; nf < 2; nf++)
          acc[mf][nf] = __builtin_amdgcn_mfma_f32_16x16x32_bf16(fA[mf][kk], fB[nf][kk], acc[mf][nf], 0, 0, 0);
    __builtin_amdgcn_s_setprio(0);
    SBAR();

    // ---- P2 ----
#pragma unroll
    for (int mf = 0; mf < 4; mf++)
#pragma unroll
      for (int kk = 0; kk < 2; kk++)
        fA[mf][kk] = *(const bf16x8*)(ac + ((aoff + (mf + 4) * 2048 + kk * 64) ^ fl));
    if (t + 2 < NT) STAGE_B(t + 2, bc);
    SBAR();
    LGKM0();
    __builtin_amdgcn_s_setprio(1);
#pragma unroll
    for (int kk = 0; kk < 2; kk++)
#pragma unroll
      for (int mf = 0; mf < 4; mf++)
#pragma unroll
        for (int nf = 0; nf < 2; nf++)
          acc[mf + 4][nf] = __builtin_amdgcn_mfma_f32_16x16x32_bf16(fA[mf][kk], fB[nf][kk], acc[mf + 4][nf], 0, 0, 0);
    __builtin_amdgcn_s_setprio(0);
    SBAR();

    // ---- P3: stage A0(t+2); boundary ----
    if (t + 2 < NT) {
      STAGE_A(t + 2, 0, ac);
      asm volatile("s_waitcnt vmcnt(4)" ::: "memory");
      SBAR();
    } else if (t + 1 < NT) {
      asm volatile("s_waitcnt vmcnt(0)" ::: "memory");
      SBAR();
    }
  }

#pragma unroll
  for (int mf = 0; mf < 8; mf++)
#pragma unroll
    for (int nf = 0; nf < 2; nf++)
#pragma unroll
      for (int r = 0; r < 4; r++) {
        size_t row = (size_t)row0 + wm * 128 + mf * 16 + l4 * 4 + r;
        size_t col = (size_t)col0 + wn * 32 + nf * 16 + l15;
        C[row * (size_t)ldc + col] = f2bf(acc[mf][nf][r]);
      }
#undef STAGE_A
#undef STAGE_B
}

// ---------------- causal GQA flash attention v3 (unchanged, round-7 proven) ----------------
__global__ __launch_bounds__(256, 2) void attn_fwd(const u16* __restrict__ qkv,
                                                   const u16* __restrict__ vtg,
                                                   u16* __restrict__ out) {
  constexpr int S = 2048, F = 6144, E = 4096;
  __shared__ __align__(16) u16 Kt[2 * 8192];
  __shared__ __align__(16) u16 Vt[2 * 8192];

  const int tid = threadIdx.x;
  const int w = tid >> 6, lane = tid & 63;
  const int l31 = lane & 31, hi = lane >> 5;
  const int pair = blockIdx.x;  // 0..7
  const int b = blockIdx.y >> 5, h = blockIdx.y & 31, kvh = h >> 2;
  const size_t rowB = (size_t)b * S;
  const float sc = 0.08838834764831845f * 1.4426950408889634f;  // 1/sqrt(128)*log2(e)
  const int sgn = tid >> 4, sgc = tid & 15;
  const size_t vtb = (size_t)(b * 8 + kvh) * 32 * 8192;

  auto stage = [&](int j, int buf) {
    char* kd = ((char*)Kt) + buf * 16384 + w * 1024;
    char* vd = ((char*)Vt) + buf * 16384 + w * 1024;
    const u16* vs = vtg + vtb + (size_t)j * 8192 + tid * 8;
#pragma unroll
    for (int p = 0; p < 4; p++) {
      int n = p * 16 + sgn;
      const u16* g = qkv + (rowB + j * 64 + n) * F + 4096 + kvh * 128 + (sgc ^ (n & 7)) * 8;
      gload_lds16(g, kd + p * 4096);
      gload_lds16(vs + p * 2048, vd + p * 4096);
    }
  };

  for (int half = 0; half < 2; ++half) {
    const int t = half ? 15 - pair : pair;
    const int nt = 2 * t + 2;
    const int r0 = t * 128;
    const int qg = r0 + w * 32 + l31;

    bf16x8 qf[8];
    {
      const u16* qp = qkv + (rowB + qg) * F + h * 128 + hi * 8;
#pragma unroll
      for (int ds = 0; ds < 8; ds++) qf[ds] = *reinterpret_cast<const bf16x8*>(qp + ds * 16);
    }

    f32x16 acco[4] = {};
    float m = -1e30f, l = 0.f;

    stage(0, 0);
    __syncthreads();

    for (int j = 0; j < nt; ++j) {
      const int cur = j & 1;
      if (j + 1 < nt) stage(j + 1, cur ^ 1);

      const char* kbase = ((const char*)Kt) + cur * 16384;
      f32x16 s0 = {}, s1 = {};
      __builtin_amdgcn_s_setprio(1);
#pragma unroll
      for (int ds = 0; ds < 8; ds++) {
        int ch = ((2 * ds + hi) ^ (l31 & 7)) << 4;
        bf16x8 k0 = *reinterpret_cast<const bf16x8*>(kbase + l31 * 256 + ch);
        bf16x8 k1 = *reinterpret_cast<const bf16x8*>(kbase + (32 + l31) * 256 + ch);
        s0 = __builtin_amdgcn_mfma_f32_32x32x16_bf16(k0, qf[ds], s0, 0, 0, 0);
        s1 = __builtin_amdgcn_mfma_f32_32x32x16_bf16(k1, qf[ds], s1, 0, 0, 0);
      }
      __builtin_amdgcn_s_setprio(0);

      f32x16 px0, px1;
      if (j >= 2 * t) {
#pragma unroll
        for (int rg = 0; rg < 16; rg++) {
          int kv0 = j * 64 + (rg & 3) + 8 * (rg >> 2) + 4 * hi;
          px0[rg] = (kv0 > qg) ? -1e30f : s0[rg] * sc;
          px1[rg] = (kv0 + 32 > qg) ? -1e30f : s1[rg] * sc;
        }
      } else {
#pragma unroll
        for (int rg = 0; rg < 16; rg++) {
          px0[rg] = s0[rg] * sc;
          px1[rg] = s1[rg] * sc;
        }
      }

      float mt[8];
#pragma unroll
      for (int i = 0; i < 8; i++)
        mt[i] = fmaxf(fmaxf(px0[i], px0[i + 8]), fmaxf(px1[i], px1[i + 8]));
#pragma unroll
      for (int stp = 4; stp; stp >>= 1)
#pragma unroll
        for (int i = 0; i < stp; i++) mt[i] = fmaxf(mt[i], mt[i + stp]);
      float pm = fmaxf(mt[0], __shfl_xor(mt[0], 32));

      if (__any(pm > m + 8.0f)) {
        float mn = fmaxf(m, pm);
        float fr = exp2f(m - mn);
        m = mn;
        l *= fr;
#pragma unroll
        for (int rg = 0; rg < 16; rg++) {
          int qrow = (rg & 3) + 8 * (rg >> 2) + 4 * hi;
          float frq = __builtin_bit_cast(
              float, __builtin_amdgcn_ds_bpermute(qrow << 2, __builtin_bit_cast(int, fr)));
          acco[0][rg] *= frq;
          acco[1][rg] *= frq;
          acco[2][rg] *= frq;
          acco[3][rg] *= frq;
        }
      }

#pragma unroll
      for (int rg = 0; rg < 16; rg++) {
        px0[rg] = exp2f(px0[rg] - m);
        px1[rg] = exp2f(px1[rg] - m);
      }
      float at[8];
#pragma unroll
      for (int i = 0; i < 8; i++)
        at[i] = (px0[i] + px0[i + 8]) + (px1[i] + px1[i + 8]);
#pragma unroll
      for (int stp = 4; stp; stp >>= 1)
#pragma unroll
        for (int i = 0; i < stp; i++) at[i] += at[i + stp];
      l += at[0] + __shfl_xor(at[0], 32);

      const char* vbase = ((const char*)Vt) + cur * 16384;
      __builtin_amdgcn_s_setprio(1);
#define PV_STEP(PH, SS)                                                               \
  {                                                                                   \
    uint32_t X0 = cvtpk(PH[((SS)&1) * 8 + 0], PH[((SS)&1) * 8 + 1]);                  \
    uint32_t Y0 = cvtpk(PH[((SS)&1) * 8 + 4], PH[((SS)&1) * 8 + 5]);                  \
    uint32_t X1 = cvtpk(PH[((SS)&1) * 8 + 2], PH[((SS)&1) * 8 + 3]);                  \
    uint32_t Y1 = cvtpk(PH[((SS)&1) * 8 + 6], PH[((SS)&1) * 8 + 7]);                  \
    plswap(X0, Y0);                                                                   \
    plswap(X1, Y1);                                                                   \
    u32x4 pw = {X0, X1, Y0, Y1};                                                      \
    bf16x8 pa = __builtin_bit_cast(bf16x8, pw);                                       \
    _Pragma("unroll") for (int df = 0; df < 4; df++) {                                \
      bf16x8 vf = *reinterpret_cast<const bf16x8*>(                                   \
          vbase + (32 * df + l31) * 128 + (((2 * (SS) + hi) ^ (l31 & 7)) << 4));      \
      acco[df] = __builtin_amdgcn_mfma_f32_32x32x16_bf16(pa, vf, acco[df], 0, 0, 0);  \
    }                                                                                 \
  }
      PV_STEP(px0, 0)
      PV_STEP(px0, 1)
      PV_STEP(px1, 2)
      PV_STEP(px1, 3)
#undef PV_STEP
      __builtin_amdgcn_s_setprio(0);

      __syncthreads();
    }

    float linv = 1.f / l;
#pragma unroll
    for (int rg = 0; rg < 16; rg++) {
      int qrow = (rg & 3) + 8 * (rg >> 2) + 4 * hi;
      float lv = __builtin_bit_cast(
          float, __builtin_amdgcn_ds_bpermute(qrow << 2, __builtin_bit_cast(int, linv)));
      size_t row = rowB + r0 + w * 32 + qrow;
      u16* op = out + row * E + h * 128 + l31;
#pragma unroll
      for (int df = 0; df < 4; df++) op[df * 32] = f2bf(acco[df][rg] * lv);
    }
  }
}

extern "C" void kernel_launch(void* const* d_in, const int* in_sizes, int n_in,
                              void* d_out, int out_size, void* d_ws, size_t ws_size,
                              hipStream_t stream) {
  const float* x = (const float*)d_in[0];
  const float* w_in = (const float*)d_in[1];
  const float* w_out = (const float*)d_in[2];
  float* out = (float*)d_out;
  char* ws = (char*)d_ws;

  u16* xb = (u16*)(ws);                                   // 33,554,432 B (reused as attn out)
  u16* wib = (u16*)(ws + 33554432ull);                    // 50,331,648 B (reused as V^T images)
  u16* wob = (u16*)(ws + 83886080ull);                    // 33,554,432 B
  u16* qkvb = (u16*)(ws + 117440512ull);                  // 50,331,648 B
  float* ct = (float*)(ws + 167772160ull);                // 524,288 B
  float* st = ct + 2048 * 64;                             // 524,288 B
  u16* attnb = xb;
  u16* vtg = wib;

  cvt_bf16<<<8192, 256, 0, stream>>>(x, xb, 16777216);
  cvt_bf16<<<12288, 256, 0, stream>>>(w_in, wib, 25165824);
  cvt_bf16<<<8192, 256, 0, stream>>>(w_out, wob, 16777216);
  rope_table<<<512, 256, 0, stream>>>(ct, st);
  gemm256<u16><<<256, 512, 0, stream>>>(xb, wib, qkvb, 4096, 4096, 4096, 6144);
  gemm_bn128<<<256, 512, 0, stream>>>(xb, wib + (size_t)4096 * 4096, qkvb + 4096, 4096, 2048, 4096, 6144);
  rope_apply<<<5120, 256, 0, stream>>>(qkvb, ct, st);
  prep_vt<<<512, 256, 0, stream>>>(qkvb, vtg);
  attn_fwd<<<dim3(8, 64), 256, 0, stream>>>(qkvb, vtg, attnb);
  gemm256<float><<<256, 512, 0, stream>>>(attnb, wob, out, 4096, 4096, 4096, 4096);
}

// Round 12
// 506.578 us; speedup vs baseline: 3.4614x; 3.4614x over previous
//
#include <hip/hip_runtime.h>
#include <hip/hip_bf16.h>
#include <stdint.h>

typedef unsigned short u16;
typedef __bf16 bf16x8 __attribute__((ext_vector_type(8)));
typedef u16 u16x8 __attribute__((ext_vector_type(8)));
typedef float f32x4 __attribute__((ext_vector_type(4)));
typedef float f32x16 __attribute__((ext_vector_type(16)));
typedef uint32_t u32x4 __attribute__((ext_vector_type(4)));

#define DEV __device__ __forceinline__
#define SBAR() asm volatile("s_barrier" ::: "memory")
#define SCHEDB() __builtin_amdgcn_sched_barrier(0)
#define LGKM0() do { asm volatile("s_waitcnt lgkmcnt(0)" ::: "memory"); SCHEDB(); } while (0)

DEV u16 f2bf(float f) {
  uint32_t u = __builtin_bit_cast(uint32_t, f);
  return (u16)((u + 0x7FFFu + ((u >> 16) & 1u)) >> 16);
}
DEV float bf2f(u16 h) { return __builtin_bit_cast(float, (uint32_t)h << 16); }

DEV void gload_lds16(const void* g, void* l) {
  __builtin_amdgcn_global_load_lds((const __attribute__((address_space(1))) uint32_t*)g,
                                   (__attribute__((address_space(3))) uint32_t*)l, 16, 0, 0);
}

DEV uint32_t cvtpk(float lo, float hi) {
  uint32_t r;
  asm("v_cvt_pk_bf16_f32 %0, %1, %2" : "=v"(r) : "v"(lo), "v"(hi));
  return r;
}
DEV void plswap(uint32_t& a, uint32_t& b) {
  asm("v_permlane32_swap_b32 %0, %1" : "+v"(a), "+v"(b));
}

// ---------------- elementwise f32 -> bf16 cast ----------------
__global__ void cvt_bf16(const float* __restrict__ in, u16* __restrict__ out, int n) {
  int i = (blockIdx.x * 256 + threadIdx.x) * 8;
  if (i >= n) return;
  const float4* p = reinterpret_cast<const float4*>(in + i);
  float4 a = p[0], b = p[1];
  u16x8 o;
  o[0] = f2bf(a.x); o[1] = f2bf(a.y); o[2] = f2bf(a.z); o[3] = f2bf(a.w);
  o[4] = f2bf(b.x); o[5] = f2bf(b.y); o[6] = f2bf(b.z); o[7] = f2bf(b.w);
  *reinterpret_cast<u16x8*>(out + i) = o;
}

// ---------------- RoPE cos/sin table (S=2048, 64 pairs) ----------------
__global__ void rope_table(float* __restrict__ ct, float* __restrict__ st) {
  int i = blockIdx.x * 256 + threadIdx.x;
  int s = i >> 6, d = i & 63;
  float invf = powf(10000.0f, -(float)d * (1.0f / 64.0f));
  float ang = (float)s * invf;
  ct[i] = cosf(ang);
  st[i] = sinf(ang);
}

// ---------------- RoPE applied in-place on bf16 qkv ----------------
__global__ void rope_apply(u16* __restrict__ qkv, const float* __restrict__ ct, const float* __restrict__ st) {
  int idx = blockIdx.x * 256 + threadIdx.x;
  int grp = idx & 7;
  int head = (idx >> 3) % 40;
  int row = idx / 320;
  int s = row & 2047;
  size_t f0 = head < 32 ? (size_t)head * 128 : (size_t)4096 + (size_t)(head - 32) * 128;
  u16* p = qkv + (size_t)row * 6144 + f0 + grp * 8;
  u16x8 a = *reinterpret_cast<const u16x8*>(p);
  u16x8 b = *reinterpret_cast<const u16x8*>(p + 64);
  const float4* cp = reinterpret_cast<const float4*>(ct + s * 64 + grp * 8);
  const float4* sp = reinterpret_cast<const float4*>(st + s * 64 + grp * 8);
  float4 c0 = cp[0], c1 = cp[1], s0 = sp[0], s1 = sp[1];
  float cc[8] = {c0.x, c0.y, c0.z, c0.w, c1.x, c1.y, c1.z, c1.w};
  float ss[8] = {s0.x, s0.y, s0.z, s0.w, s1.x, s1.y, s1.z, s1.w};
  u16x8 o1, o2;
#pragma unroll
  for (int i = 0; i < 8; i++) {
    float x1 = bf2f(a[i]), x2 = bf2f(b[i]);
    o1[i] = f2bf(x1 * cc[i] - x2 * ss[i]);
    o2[i] = f2bf(x2 * cc[i] + x1 * ss[i]);
  }
  *reinterpret_cast<u16x8*>(p) = o1;
  *reinterpret_cast<u16x8*>(p + 64) = o2;
}

// ---------------- V^T tile image prep ----------------
__global__ void prep_vt(const u16* __restrict__ qkv, u16* __restrict__ vtg) {
  int id = blockIdx.x;  // (b*8+kvh)*32 + j
  int j = id & 31, kvh = (id >> 5) & 7, b = id >> 8;
  const int tid = threadIdx.x;
  const size_t rowB = (size_t)b * 2048;
  u16* img = vtg + (size_t)id * 8192;
#pragma unroll
  for (int p = 0; p < 4; p++) {
    int lin = p * 256 + tid;
    int d = lin >> 3, c = lin & 7;
    const u16* src = qkv + (rowB + j * 64 + c * 8) * 6144 + 5120 + kvh * 128 + d;
    u16x8 v;
#pragma unroll
    for (int i = 0; i < 8; i++) v[i] = src[(size_t)i * 6144];
    *reinterpret_cast<u16x8*>(img + d * 64 + ((c ^ (d & 7)) << 3)) = v;
  }
}

// ---------------- GEMM epilogue store helpers ----------------
DEV void store_c(float* C, size_t idx, float v) { C[idx] = v; }
DEV void store_c(u16* C, size_t idx, float v) { C[idx] = f2bf(v); }

// ---------------- 256x256 GEMM, 2-barrier/K-tile schedule (round-8 proven, 507.6us config) ----------------
// NOTE (register wall, rounds 10/11): a 512-thread block = 2 waves/SIMD resident by
// construction -> hard cap 256 total regs/wave (arch+acc). acc = 128, so arch-VGPR
// headroom ~128 — this schedule exactly fits (VGPR_Count 124). Deeper read-pipelining
// needs ~160 arch VGPR -> structural spill. Do not re-attempt within this block shape.
template <typename OutT>
__global__ __launch_bounds__(512, 2) void gemm256(const u16* __restrict__ A, const u16* __restrict__ B,
                                                  OutT* __restrict__ C, int M, int N, int K, int ldc) {
  __shared__ __align__(16) u16 lds[65536];  // 128 KiB
  char* LB = (char*)lds;
  const int tid = threadIdx.x;
  const int w = tid >> 6, lane = tid & 63;
  const int l15 = lane & 15, l4 = lane >> 4;
  const int wm = w >> 2, wn = w & 3;

  int nwg = gridDim.x;
  int q = nwg >> 3, rr = nwg & 7;
  int xcd = blockIdx.x & 7, idx = blockIdx.x >> 3;
  int sw = (xcd < rr ? xcd * (q + 1) : rr * (q + 1) + (xcd - rr) * q) + idx;
  int gxn = N >> 8;
  int by = sw / gxn, bx = sw - by * gxn;
  const int row0 = by << 8, col0 = bx << 8;
  const int NT = K >> 6;

  const int srow = w * 8 + (lane >> 3);
  const int sc16 = (lane & 7) ^ ((lane >> 3) & 7);
  const u16* gA = A + (size_t)(row0 + srow) * K + sc16 * 8;
  const u16* gB = B + (size_t)(col0 + srow) * K + sc16 * 8;

  const int fl = (l15 & 7) << 4;
  const int aoff = (wm * 128 + l15) * 128 + l4 * 16;
  const int boff = (wn * 64 + l15) * 128 + l4 * 16;

  f32x4 acc[8][4] = {};
  bf16x8 fA[4][2], fB0[2][2], fBc[2][2];

#define STAGE_A(kt, h, base)                                                      \
  {                                                                               \
    const u16* g_ = gA + (size_t)((h)*128) * K + (size_t)(kt)*64;                 \
    gload_lds16(g_, (base) + (h)*16384 + w * 1024);                               \
    gload_lds16(g_ + (size_t)64 * K, (base) + (h)*16384 + 8192 + w * 1024);       \
  }
#define STAGE_B(kt, h, base)                                                      \
  {                                                                               \
    const u16* g_ = gB + (size_t)((h)*128) * K + (size_t)(kt)*64;                 \
    gload_lds16(g_, (base) + (h)*16384 + w * 1024);                               \
    gload_lds16(g_ + (size_t)64 * K, (base) + (h)*16384 + 8192 + w * 1024);       \
  }
#define MFMA_Q(FB, MH, NH)                                                        \
  _Pragma("unroll") for (int kk = 0; kk < 2; kk++) {                              \
    _Pragma("unroll") for (int mf = 0; mf < 4; mf++) {                            \
      _Pragma("unroll") for (int nf = 0; nf < 2; nf++) {                          \
        acc[(MH)*4 + mf][(NH)*2 + nf] = __builtin_amdgcn_mfma_f32_16x16x32_bf16(  \
            fA[mf][kk], FB[nf][kk], acc[(MH)*4 + mf][(NH)*2 + nf], 0, 0, 0);      \
      }                                                                           \
    }                                                                             \
  }

  // prologue: tile0 {A0,A1,B0,B1} -> buf0; tile1 {A0,B0,B1} -> buf1 (A1(1) at t=0 start)
  STAGE_A(0, 0, LB);
  STAGE_A(0, 1, LB);
  STAGE_B(0, 0, LB + 65536);
  STAGE_B(0, 1, LB + 65536);
  STAGE_A(1, 0, LB + 32768);
  STAGE_B(1, 0, LB + 98304);
  STAGE_B(1, 1, LB + 98304);
  asm volatile("s_waitcnt vmcnt(6)" ::: "memory");
  SBAR();

  for (int t = 0; t < NT; ++t) {
    char* ac = LB + (t & 1) * 32768;
    char* bc = LB + 65536 + (t & 1) * 32768;
    char* an = LB + ((t + 1) & 1) * 32768;

    // stage A1(t+1) into other buffer (its region was last read in tile t-1)
    if (t + 1 < NT) STAGE_A(t + 1, 1, an);

    // ---- reads: fA-1st (8), fB0 (4), fBc (4) — group order pinned ----
#pragma unroll
    for (int mf = 0; mf < 4; mf++)
#pragma unroll
      for (int kk = 0; kk < 2; kk++)
        fA[mf][kk] = *(const bf16x8*)(ac + ((aoff + mf * 2048 + kk * 64) ^ fl));
    SCHEDB();
#pragma unroll
    for (int nf = 0; nf < 2; nf++)
#pragma unroll
      for (int kk = 0; kk < 2; kk++)
        fB0[nf][kk] = *(const bf16x8*)(bc + ((boff + nf * 2048 + kk * 64) ^ fl));
    SCHEDB();
#pragma unroll
    for (int nf = 0; nf < 2; nf++)
#pragma unroll
      for (int kk = 0; kk < 2; kk++)
        fBc[nf][kk] = *(const bf16x8*)(bc + ((boff + (nf + 2) * 2048 + kk * 64) ^ fl));
    SCHEDB();

    // ---- Q00: fA1st + fB0 ready (keep 4 newest = fBc outstanding) ----
    asm volatile("s_waitcnt lgkmcnt(4)" ::: "memory");
    SCHEDB();
    __builtin_amdgcn_s_setprio(1);
    MFMA_Q(fB0, 0, 0);
    __builtin_amdgcn_s_setprio(0);

    // ---- Q01: fBc ready ----
    asm volatile("s_waitcnt lgkmcnt(0)" ::: "memory");
    SCHEDB();
    __builtin_amdgcn_s_setprio(1);
    MFMA_Q(fBc, 0, 1);
    __builtin_amdgcn_s_setprio(0);

    // ---- reads: fA-2nd (8, reuse fA regs) ----
#pragma unroll
    for (int mf = 0; mf < 4; mf++)
#pragma unroll
      for (int kk = 0; kk < 2; kk++)
        fA[mf][kk] = *(const bf16x8*)(ac + ((aoff + (mf + 4) * 2048 + kk * 64) ^ fl));
    asm volatile("s_waitcnt lgkmcnt(0)" ::: "memory");
    SCHEDB();

    // ---- mid barrier: ALL waves' tile-t reads complete -> safe to overwrite ----
    SBAR();
    if (t + 2 < NT) {
      STAGE_B(t + 2, 0, bc);
      STAGE_B(t + 2, 1, bc);
      STAGE_A(t + 2, 0, ac);
    }
    __builtin_amdgcn_s_setprio(1);
    MFMA_Q(fBc, 1, 1);
    MFMA_Q(fB0, 1, 0);
    __builtin_amdgcn_s_setprio(0);

    // ---- boundary: keep 6 newest (t+2 mid-stages); everything for t+1 resident ----
    if (t + 2 < NT) {
      asm volatile("s_waitcnt vmcnt(6)" ::: "memory");
      SBAR();
    } else if (t + 1 < NT) {
      asm volatile("s_waitcnt vmcnt(0)" ::: "memory");
      SBAR();
    }
  }

#pragma unroll
  for (int mf = 0; mf < 8; mf++)
#pragma unroll
    for (int nf = 0; nf < 4; nf++)
#pragma unroll
      for (int r = 0; r < 4; r++) {
        size_t row = (size_t)row0 + wm * 128 + mf * 16 + l4 * 4 + r;
        size_t col = (size_t)col0 + wn * 64 + nf * 16 + l15;
        store_c(C, row * (size_t)ldc + col, acc[mf][nf][r]);
      }
#undef STAGE_A
#undef STAGE_B
#undef MFMA_Q
}

// ---------------- 256x128 GEMM, 2-barrier/K-tile (gemm1 K/V columns; round-8 proven) ----------------
__global__ __launch_bounds__(512, 2) void gemm_bn128(const u16* __restrict__ A, const u16* __restrict__ B,
                                                     u16* __restrict__ C, int M, int N, int K, int ldc) {
  __shared__ __align__(16) u16 lds[49152];  // 96 KiB
  char* LB = (char*)lds;
  const int tid = threadIdx.x;
  const int w = tid >> 6, lane = tid & 63;
  const int l15 = lane & 15, l4 = lane >> 4;
  const int wm = w >> 2, wn = w & 3;

  int nwg = gridDim.x;
  int q = nwg >> 3, rr = nwg & 7;
  int xcd = blockIdx.x & 7, idx = blockIdx.x >> 3;
  int sw = (xcd < rr ? xcd * (q + 1) : rr * (q + 1) + (xcd - rr) * q) + idx;
  int gxn = N >> 7;
  int by = sw / gxn, bx = sw - by * gxn;
  const int row0 = by << 8, col0 = bx << 7;
  const int NT = K >> 6;

  const int srow = w * 8 + (lane >> 3);
  const int sc16 = (lane & 7) ^ ((lane >> 3) & 7);
  const u16* gA = A + (size_t)(row0 + srow) * K + sc16 * 8;
  const u16* gB = B + (size_t)(col0 + srow) * K + sc16 * 8;

  const int fl = (l15 & 7) << 4;
  const int aoff = (wm * 128 + l15) * 128 + l4 * 16;
  const int boff = (wn * 32 + l15) * 128 + l4 * 16;

  f32x4 acc[8][2] = {};
  bf16x8 fA[4][2], fB[2][2];

#define STAGE_A(kt, h, base)                                                      \
  {                                                                               \
    const u16* g_ = gA + (size_t)((h)*128) * K + (size_t)(kt)*64;                 \
    gload_lds16(g_, (base) + (h)*16384 + w * 1024);                               \
    gload_lds16(g_ + (size_t)64 * K, (base) + (h)*16384 + 8192 + w * 1024);       \
  }
#define STAGE_B(kt, base)                                                         \
  {                                                                               \
    const u16* g_ = gB + (size_t)(kt)*64;                                         \
    gload_lds16(g_, (base) + w * 1024);                                           \
    gload_lds16(g_ + (size_t)64 * K, (base) + 8192 + w * 1024);                   \
  }

  STAGE_A(0, 0, LB);
  STAGE_A(0, 1, LB);
  STAGE_B(0, LB + 65536);
  STAGE_A(1, 0, LB + 32768);
  STAGE_B(1, LB + 65536 + 16384);
  asm volatile("s_waitcnt vmcnt(4)" ::: "memory");
  SBAR();

  for (int t = 0; t < NT; ++t) {
    char* ac = LB + (t & 1) * 32768;
    char* bc = LB + 65536 + (t & 1) * 16384;
    char* an = LB + ((t + 1) & 1) * 32768;

    if (t + 1 < NT) STAGE_A(t + 1, 1, an);

    // ---- reads: fA-1st (8) + fB (4) ----
#pragma unroll
    for (int mf = 0; mf < 4; mf++)
#pragma unroll
      for (int kk = 0; kk < 2; kk++)
        fA[mf][kk] = *(const bf16x8*)(ac + ((aoff + mf * 2048 + kk * 64) ^ fl));
#pragma unroll
    for (int nf = 0; nf < 2; nf++)
#pragma unroll
      for (int kk = 0; kk < 2; kk++)
        fB[nf][kk] = *(const bf16x8*)(bc + ((boff + nf * 2048 + kk * 64) ^ fl));
    SCHEDB();
    asm volatile("s_waitcnt lgkmcnt(0)" ::: "memory");
    SCHEDB();
    __builtin_amdgcn_s_setprio(1);
#pragma unroll
    for (int kk = 0; kk < 2; kk++)
#pragma unroll
      for (int mf = 0; mf < 4; mf++)
#pragma unroll
        for (int nf = 0; nf < 2; nf++)
          acc[mf][nf] = __builtin_amdgcn_mfma_f32_16x16x32_bf16(fA[mf][kk], fB[nf][kk], acc[mf][nf], 0, 0, 0);
    __builtin_amdgcn_s_setprio(0);

    // ---- reads: fA-2nd (8) ----
#pragma unroll
    for (int mf = 0; mf < 4; mf++)
#pragma unroll
      for (int kk = 0; kk < 2; kk++)
        fA[mf][kk] = *(const bf16x8*)(ac + ((aoff + (mf + 4) * 2048 + kk * 64) ^ fl));
    asm volatile("s_waitcnt lgkmcnt(0)" ::: "memory");
    SCHEDB();

    SBAR();  // all reads done
    if (t + 2 < NT) {
      STAGE_A(t + 2, 0, ac);
      STAGE_B(t + 2, bc);
    }
    __builtin_amdgcn_s_setprio(1);
#pragma unroll
    for (int kk = 0; kk < 2; kk++)
#pragma unroll
      for (int mf = 0; mf < 4; mf++)
#pragma unroll
        for (int nf = 0; nf < 2; nf++)
          acc[mf + 4][nf] = __builtin_amdgcn_mfma_f32_16x16x32_bf16(fA[mf][kk], fB[nf][kk], acc[mf + 4][nf], 0, 0, 0);
    __builtin_amdgcn_s_setprio(0);

    if (t + 2 < NT) {
      asm volatile("s_waitcnt vmcnt(4)" ::: "memory");
      SBAR();
    } else if (t + 1 < NT) {
      asm volatile("s_waitcnt vmcnt(0)" ::: "memory");
      SBAR();
    }
  }

#pragma unroll
  for (int mf = 0; mf < 8; mf++)
#pragma unroll
    for (int nf = 0; nf < 2; nf++)
#pragma unroll
      for (int r = 0; r < 4; r++) {
        size_t row = (size_t)row0 + wm * 128 + mf * 16 + l4 * 4 + r;
        size_t col = (size_t)col0 + wn * 32 + nf * 16 + l15;
        C[row * (size_t)ldc + col] = f2bf(acc[mf][nf][r]);
      }
#undef STAGE_A
#undef STAGE_B
}

// ---------------- causal GQA flash attention v3 (round-7 proven) ----------------
__global__ __launch_bounds__(256, 2) void attn_fwd(const u16* __restrict__ qkv,
                                                   const u16* __restrict__ vtg,
                                                   u16* __restrict__ out) {
  constexpr int S = 2048, F = 6144, E = 4096;
  __shared__ __align__(16) u16 Kt[2 * 8192];
  __shared__ __align__(16) u16 Vt[2 * 8192];

  const int tid = threadIdx.x;
  const int w = tid >> 6, lane = tid & 63;
  const int l31 = lane & 31, hi = lane >> 5;
  const int pair = blockIdx.x;  // 0..7
  const int b = blockIdx.y >> 5, h = blockIdx.y & 31, kvh = h >> 2;
  const size_t rowB = (size_t)b * S;
  const float sc = 0.08838834764831845f * 1.4426950408889634f;  // 1/sqrt(128)*log2(e)
  const int sgn = tid >> 4, sgc = tid & 15;
  const size_t vtb = (size_t)(b * 8 + kvh) * 32 * 8192;

  auto stage = [&](int j, int buf) {
    char* kd = ((char*)Kt) + buf * 16384 + w * 1024;
    char* vd = ((char*)Vt) + buf * 16384 + w * 1024;
    const u16* vs = vtg + vtb + (size_t)j * 8192 + tid * 8;
#pragma unroll
    for (int p = 0; p < 4; p++) {
      int n = p * 16 + sgn;
      const u16* g = qkv + (rowB + j * 64 + n) * F + 4096 + kvh * 128 + (sgc ^ (n & 7)) * 8;
      gload_lds16(g, kd + p * 4096);
      gload_lds16(vs + p * 2048, vd + p * 4096);
    }
  };

  for (int half = 0; half < 2; ++half) {
    const int t = half ? 15 - pair : pair;
    const int nt = 2 * t + 2;
    const int r0 = t * 128;
    const int qg = r0 + w * 32 + l31;

    bf16x8 qf[8];
    {
      const u16* qp = qkv + (rowB + qg) * F + h * 128 + hi * 8;
#pragma unroll
      for (int ds = 0; ds < 8; ds++) qf[ds] = *reinterpret_cast<const bf16x8*>(qp + ds * 16);
    }

    f32x16 acco[4] = {};
    float m = -1e30f, l = 0.f;

    stage(0, 0);
    __syncthreads();

    for (int j = 0; j < nt; ++j) {
      const int cur = j & 1;
      if (j + 1 < nt) stage(j + 1, cur ^ 1);

      const char* kbase = ((const char*)Kt) + cur * 16384;
      f32x16 s0 = {}, s1 = {};
      __builtin_amdgcn_s_setprio(1);
#pragma unroll
      for (int ds = 0; ds < 8; ds++) {
        int ch = ((2 * ds + hi) ^ (l31 & 7)) << 4;
        bf16x8 k0 = *reinterpret_cast<const bf16x8*>(kbase + l31 * 256 + ch);
        bf16x8 k1 = *reinterpret_cast<const bf16x8*>(kbase + (32 + l31) * 256 + ch);
        s0 = __builtin_amdgcn_mfma_f32_32x32x16_bf16(k0, qf[ds], s0, 0, 0, 0);
        s1 = __builtin_amdgcn_mfma_f32_32x32x16_bf16(k1, qf[ds], s1, 0, 0, 0);
      }
      __builtin_amdgcn_s_setprio(0);

      f32x16 px0, px1;
      if (j >= 2 * t) {
#pragma unroll
        for (int rg = 0; rg < 16; rg++) {
          int kv0 = j * 64 + (rg & 3) + 8 * (rg >> 2) + 4 * hi;
          px0[rg] = (kv0 > qg) ? -1e30f : s0[rg] * sc;
          px1[rg] = (kv0 + 32 > qg) ? -1e30f : s1[rg] * sc;
        }
      } else {
#pragma unroll
        for (int rg = 0; rg < 16; rg++) {
          px0[rg] = s0[rg] * sc;
          px1[rg] = s1[rg] * sc;
        }
      }

      float mt[8];
#pragma unroll
      for (int i = 0; i < 8; i++)
        mt[i] = fmaxf(fmaxf(px0[i], px0[i + 8]), fmaxf(px1[i], px1[i + 8]));
#pragma unroll
      for (int stp = 4; stp; stp >>= 1)
#pragma unroll
        for (int i = 0; i < stp; i++) mt[i] = fmaxf(mt[i], mt[i + stp]);
      float pm = fmaxf(mt[0], __shfl_xor(mt[0], 32));

      if (__any(pm > m + 8.0f)) {
        float mn = fmaxf(m, pm);
        float fr = exp2f(m - mn);
        m = mn;
        l *= fr;
#pragma unroll
        for (int rg = 0; rg < 16; rg++) {
          int qrow = (rg & 3) + 8 * (rg >> 2) + 4 * hi;
          float frq = __builtin_bit_cast(
              float, __builtin_amdgcn_ds_bpermute(qrow << 2, __builtin_bit_cast(int, fr)));
          acco[0][rg] *= frq;
          acco[1][rg] *= frq;
          acco[2][rg] *= frq;
          acco[3][rg] *= frq;
        }
      }

#pragma unroll
      for (int rg = 0; rg < 16; rg++) {
        px0[rg] = exp2f(px0[rg] - m);
        px1[rg] = exp2f(px1[rg] - m);
      }
      float at[8];
#pragma unroll
      for (int i = 0; i < 8; i++)
        at[i] = (px0[i] + px0[i + 8]) + (px1[i] + px1[i + 8]);
#pragma unroll
      for (int stp = 4; stp; stp >>= 1)
#pragma unroll
        for (int i = 0; i < stp; i++) at[i] += at[i + stp];
      l += at[0] + __shfl_xor(at[0], 32);

      const char* vbase = ((const char*)Vt) + cur * 16384;
      __builtin_amdgcn_s_setprio(1);
#define PV_STEP(PH, SS)                                                               \
  {                                                                                   \
    uint32_t X0 = cvtpk(PH[((SS)&1) * 8 + 0], PH[((SS)&1) * 8 + 1]);                  \
    uint32_t Y0 = cvtpk(PH[((SS)&1) * 8 + 4], PH[((SS)&1) * 8 + 5]);                  \
    uint32_t X1 = cvtpk(PH[((SS)&1) * 8 + 2], PH[((SS)&1) * 8 + 3]);                  \
    uint32_t Y1 = cvtpk(PH[((SS)&1) * 8 + 6], PH[((SS)&1) * 8 + 7]);                  \
    plswap(X0, Y0);                                                                   \
    plswap(X1, Y1);                                                                   \
    u32x4 pw = {X0, X1, Y0, Y1};                                                      \
    bf16x8 pa = __builtin_bit_cast(bf16x8, pw);                                       \
    _Pragma("unroll") for (int df = 0; df < 4; df++) {                                \
      bf16x8 vf = *reinterpret_cast<const bf16x8*>(                                   \
          vbase + (32 * df + l31) * 128 + (((2 * (SS) + hi) ^ (l31 & 7)) << 4));      \
      acco[df] = __builtin_amdgcn_mfma_f32_32x32x16_bf16(pa, vf, acco[df], 0, 0, 0);  \
    }                                                                                 \
  }
      PV_STEP(px0, 0)
      PV_STEP(px0, 1)
      PV_STEP(px1, 2)
      PV_STEP(px1, 3)
#undef PV_STEP
      __builtin_amdgcn_s_setprio(0);

      __syncthreads();
    }

    float linv = 1.f / l;
#pragma unroll
    for (int rg = 0; rg < 16; rg++) {
      int qrow = (rg & 3) + 8 * (rg >> 2) + 4 * hi;
      float lv = __builtin_bit_cast(
          float, __builtin_amdgcn_ds_bpermute(qrow << 2, __builtin_bit_cast(int, linv)));
      size_t row = rowB + r0 + w * 32 + qrow;
      u16* op = out + row * E + h * 128 + l31;
#pragma unroll
      for (int df = 0; df < 4; df++) op[df * 32] = f2bf(acco[df][rg] * lv);
    }
  }
}

extern "C" void kernel_launch(void* const* d_in, const int* in_sizes, int n_in,
                              void* d_out, int out_size, void* d_ws, size_t ws_size,
                              hipStream_t stream) {
  const float* x = (const float*)d_in[0];
  const float* w_in = (const float*)d_in[1];
  const float* w_out = (const float*)d_in[2];
  float* out = (float*)d_out;
  char* ws = (char*)d_ws;

  u16* xb = (u16*)(ws);                                   // 33,554,432 B (reused as attn out)
  u16* wib = (u16*)(ws + 33554432ull);                    // 50,331,648 B (reused as V^T images)
  u16* wob = (u16*)(ws + 83886080ull);                    // 33,554,432 B
  u16* qkvb = (u16*)(ws + 117440512ull);                  // 50,331,648 B
  float* ct = (float*)(ws + 167772160ull);                // 524,288 B
  float* st = ct + 2048 * 64;                             // 524,288 B
  u16* attnb = xb;
  u16* vtg = wib;

  cvt_bf16<<<8192, 256, 0, stream>>>(x, xb, 16777216);
  cvt_bf16<<<12288, 256, 0, stream>>>(w_in, wib, 25165824);
  cvt_bf16<<<8192, 256, 0, stream>>>(w_out, wob, 16777216);
  rope_table<<<512, 256, 0, stream>>>(ct, st);
  gemm256<u16><<<256, 512, 0, stream>>>(xb, wib, qkvb, 4096, 4096, 4096, 6144);
  gemm_bn128<<<256, 512, 0, stream>>>(xb, wib + (size_t)4096 * 4096, qkvb + 4096, 4096, 2048, 4096, 6144);
  rope_apply<<<5120, 256, 0, stream>>>(qkvb, ct, st);
  prep_vt<<<512, 256, 0, stream>>>(qkvb, vtg);
  attn_fwd<<<dim3(8, 64), 256, 0, stream>>>(qkvb, vtg, attnb);
  gemm256<float><<<256, 512, 0, stream>>>(attnb, wob, out, 4096, 4096, 4096, 4096);
}

// Round 13
// 494.372 us; speedup vs baseline: 3.5468x; 1.0247x over previous
//
#include <hip/hip_runtime.h>
#include <hip/hip_bf16.h>
#include <stdint.h>

typedef unsigned short u16;
typedef __bf16 bf16x8 __attribute__((ext_vector_type(8)));
typedef u16 u16x8 __attribute__((ext_vector_type(8)));
typedef float f32x4 __attribute__((ext_vector_type(4)));
typedef float f32x16 __attribute__((ext_vector_type(16)));
typedef uint32_t u32x4 __attribute__((ext_vector_type(4)));

#define DEV __device__ __forceinline__
#define SBAR() asm volatile("s_barrier" ::: "memory")
#define SCHEDB() __builtin_amdgcn_sched_barrier(0)

DEV u16 f2bf(float f) {
  uint32_t u = __builtin_bit_cast(uint32_t, f);
  return (u16)((u + 0x7FFFu + ((u >> 16) & 1u)) >> 16);
}
DEV float bf2f(u16 h) { return __builtin_bit_cast(float, (uint32_t)h << 16); }

DEV void gload_lds16(const void* g, void* l) {
  __builtin_amdgcn_global_load_lds((const __attribute__((address_space(1))) uint32_t*)g,
                                   (__attribute__((address_space(3))) uint32_t*)l, 16, 0, 0);
}

DEV uint32_t cvtpk(float lo, float hi) {
  uint32_t r;
  asm("v_cvt_pk_bf16_f32 %0, %1, %2" : "=v"(r) : "v"(lo), "v"(hi));
  return r;
}
DEV void plswap(uint32_t& a, uint32_t& b) {
  asm("v_permlane32_swap_b32 %0, %1" : "+v"(a), "+v"(b));
}

// ---------------- fused prep: cvt x / w_in / w_out + rope table (4 launches -> 1) ----------------
DEV void cvt8(const float* __restrict__ in, u16* __restrict__ out, int i) {
  const float4* p = reinterpret_cast<const float4*>(in + i);
  float4 a = p[0], b = p[1];
  u16x8 o;
  o[0] = f2bf(a.x); o[1] = f2bf(a.y); o[2] = f2bf(a.z); o[3] = f2bf(a.w);
  o[4] = f2bf(b.x); o[5] = f2bf(b.y); o[6] = f2bf(b.z); o[7] = f2bf(b.w);
  *reinterpret_cast<u16x8*>(out + i) = o;
}

__global__ void prep_all(const float* __restrict__ x, const float* __restrict__ w_in,
                         const float* __restrict__ w_out, u16* __restrict__ xb,
                         u16* __restrict__ wib, u16* __restrict__ wob,
                         float* __restrict__ ct, float* __restrict__ st) {
  int b = blockIdx.x;
  if (b < 8192) {
    cvt8(x, xb, (b * 256 + threadIdx.x) * 8);
  } else if (b < 20480) {
    cvt8(w_in, wib, ((b - 8192) * 256 + threadIdx.x) * 8);
  } else if (b < 28672) {
    cvt8(w_out, wob, ((b - 20480) * 256 + threadIdx.x) * 8);
  } else {
    int i = (b - 28672) * 256 + threadIdx.x;  // 131072 = 2048*64
    int s = i >> 6, d = i & 63;
    float invf = powf(10000.0f, -(float)d * (1.0f / 64.0f));
    float ang = (float)s * invf;
    ct[i] = cosf(ang);
    st[i] = sinf(ang);
  }
}

// ---------------- fused rope_apply + V^T image prep (2 launches -> 1) ----------------
// blocks [0,5120): rope on Q/K; [5120,5632): V^T tile images (disjoint qkv regions)
__global__ void rope_and_vt(u16* __restrict__ qkv, const float* __restrict__ ct,
                            const float* __restrict__ st, u16* __restrict__ vtg) {
  const int tid = threadIdx.x;
  if (blockIdx.x < 5120) {
    int idx = blockIdx.x * 256 + tid;
    int grp = idx & 7;
    int head = (idx >> 3) % 40;
    int row = idx / 320;
    int s = row & 2047;
    size_t f0 = head < 32 ? (size_t)head * 128 : (size_t)4096 + (size_t)(head - 32) * 128;
    u16* p = qkv + (size_t)row * 6144 + f0 + grp * 8;
    u16x8 a = *reinterpret_cast<const u16x8*>(p);
    u16x8 b = *reinterpret_cast<const u16x8*>(p + 64);
    const float4* cp = reinterpret_cast<const float4*>(ct + s * 64 + grp * 8);
    const float4* sp = reinterpret_cast<const float4*>(st + s * 64 + grp * 8);
    float4 c0 = cp[0], c1 = cp[1], s0 = sp[0], s1 = sp[1];
    float cc[8] = {c0.x, c0.y, c0.z, c0.w, c1.x, c1.y, c1.z, c1.w};
    float ss[8] = {s0.x, s0.y, s0.z, s0.w, s1.x, s1.y, s1.z, s1.w};
    u16x8 o1, o2;
#pragma unroll
    for (int i = 0; i < 8; i++) {
      float x1 = bf2f(a[i]), x2 = bf2f(b[i]);
      o1[i] = f2bf(x1 * cc[i] - x2 * ss[i]);
      o2[i] = f2bf(x2 * cc[i] + x1 * ss[i]);
    }
    *reinterpret_cast<u16x8*>(p) = o1;
    *reinterpret_cast<u16x8*>(p + 64) = o2;
  } else {
    int id = blockIdx.x - 5120;  // (b*8+kvh)*32 + j
    int j = id & 31, kvh = (id >> 5) & 7, b = id >> 8;
    const size_t rowB = (size_t)b * 2048;
    u16* img = vtg + (size_t)id * 8192;
#pragma unroll
    for (int p = 0; p < 4; p++) {
      int lin = p * 256 + tid;
      int d = lin >> 3, c = lin & 7;
      const u16* src = qkv + (rowB + j * 64 + c * 8) * 6144 + 5120 + kvh * 128 + d;
      u16x8 v;
#pragma unroll
      for (int i = 0; i < 8; i++) v[i] = src[(size_t)i * 6144];
      *reinterpret_cast<u16x8*>(img + d * 64 + ((c ^ (d & 7)) << 3)) = v;
    }
  }
}

// ---------------- GEMM epilogue store helpers ----------------
DEV void store_c(float* C, size_t idx, float v) { C[idx] = v; }
DEV void store_c(u16* C, size_t idx, float v) { C[idx] = f2bf(v); }

// ---------------- 256x256 GEMM, 2-barrier/K-tile schedule (round-8 proven) ----------------
// NOTE (register wall, rounds 10/11): a 512-thread block = 2 waves/SIMD resident by
// construction -> hard cap 256 total regs/wave (arch+acc). acc = 128, so arch-VGPR
// headroom ~128 — this schedule exactly fits (VGPR_Count 124). Deeper read-pipelining
// needs ~160 arch VGPR -> structural spill. Do not re-attempt within this block shape.
template <typename OutT>
__global__ __launch_bounds__(512, 2) void gemm256(const u16* __restrict__ A, const u16* __restrict__ B,
                                                  OutT* __restrict__ C, int M, int N, int K, int ldc) {
  __shared__ __align__(16) u16 lds[65536];  // 128 KiB
  char* LB = (char*)lds;
  const int tid = threadIdx.x;
  const int w = tid >> 6, lane = tid & 63;
  const int l15 = lane & 15, l4 = lane >> 4;
  const int wm = w >> 2, wn = w & 3;

  int nwg = gridDim.x;
  int q = nwg >> 3, rr = nwg & 7;
  int xcd = blockIdx.x & 7, idx = blockIdx.x >> 3;
  int sw = (xcd < rr ? xcd * (q + 1) : rr * (q + 1) + (xcd - rr) * q) + idx;
  int gxn = N >> 8;
  int by = sw / gxn, bx = sw - by * gxn;
  const int row0 = by << 8, col0 = bx << 8;
  const int NT = K >> 6;

  const int srow = w * 8 + (lane >> 3);
  const int sc16 = (lane & 7) ^ ((lane >> 3) & 7);
  const u16* gA = A + (size_t)(row0 + srow) * K + sc16 * 8;
  const u16* gB = B + (size_t)(col0 + srow) * K + sc16 * 8;

  const int fl = (l15 & 7) << 4;
  const int aoff = (wm * 128 + l15) * 128 + l4 * 16;
  const int boff = (wn * 64 + l15) * 128 + l4 * 16;

  f32x4 acc[8][4] = {};
  bf16x8 fA[4][2], fB0[2][2], fBc[2][2];

#define STAGE_A(kt, h, base)                                                      \
  {                                                                               \
    const u16* g_ = gA + (size_t)((h)*128) * K + (size_t)(kt)*64;                 \
    gload_lds16(g_, (base) + (h)*16384 + w * 1024);                               \
    gload_lds16(g_ + (size_t)64 * K, (base) + (h)*16384 + 8192 + w * 1024);       \
  }
#define STAGE_B(kt, h, base)                                                      \
  {                                                                               \
    const u16* g_ = gB + (size_t)((h)*128) * K + (size_t)(kt)*64;                 \
    gload_lds16(g_, (base) + (h)*16384 + w * 1024);                               \
    gload_lds16(g_ + (size_t)64 * K, (base) + (h)*16384 + 8192 + w * 1024);       \
  }
#define MFMA_Q(FB, MH, NH)                                                        \
  _Pragma("unroll") for (int kk = 0; kk < 2; kk++) {                              \
    _Pragma("unroll") for (int mf = 0; mf < 4; mf++) {                            \
      _Pragma("unroll") for (int nf = 0; nf < 2; nf++) {                          \
        acc[(MH)*4 + mf][(NH)*2 + nf] = __builtin_amdgcn_mfma_f32_16x16x32_bf16(  \
            fA[mf][kk], FB[nf][kk], acc[(MH)*4 + mf][(NH)*2 + nf], 0, 0, 0);      \
      }                                                                           \
    }                                                                             \
  }

  // prologue: tile0 {A0,A1,B0,B1} -> buf0; tile1 {A0,B0,B1} -> buf1 (A1(1) at t=0 start)
  STAGE_A(0, 0, LB);
  STAGE_A(0, 1, LB);
  STAGE_B(0, 0, LB + 65536);
  STAGE_B(0, 1, LB + 65536);
  STAGE_A(1, 0, LB + 32768);
  STAGE_B(1, 0, LB + 98304);
  STAGE_B(1, 1, LB + 98304);
  asm volatile("s_waitcnt vmcnt(6)" ::: "memory");
  SBAR();

  for (int t = 0; t < NT; ++t) {
    char* ac = LB + (t & 1) * 32768;
    char* bc = LB + 65536 + (t & 1) * 32768;
    char* an = LB + ((t + 1) & 1) * 32768;

    // stage A1(t+1) into other buffer (its region was last read in tile t-1)
    if (t + 1 < NT) STAGE_A(t + 1, 1, an);

    // ---- reads: fA-1st (8), fB0 (4), fBc (4) — group order pinned ----
#pragma unroll
    for (int mf = 0; mf < 4; mf++)
#pragma unroll
      for (int kk = 0; kk < 2; kk++)
        fA[mf][kk] = *(const bf16x8*)(ac + ((aoff + mf * 2048 + kk * 64) ^ fl));
    SCHEDB();
#pragma unroll
    for (int nf = 0; nf < 2; nf++)
#pragma unroll
      for (int kk = 0; kk < 2; kk++)
        fB0[nf][kk] = *(const bf16x8*)(bc + ((boff + nf * 2048 + kk * 64) ^ fl));
    SCHEDB();
#pragma unroll
    for (int nf = 0; nf < 2; nf++)
#pragma unroll
      for (int kk = 0; kk < 2; kk++)
        fBc[nf][kk] = *(const bf16x8*)(bc + ((boff + (nf + 2) * 2048 + kk * 64) ^ fl));
    SCHEDB();

    // ---- Q00: fA1st + fB0 ready (keep 4 newest = fBc outstanding) ----
    asm volatile("s_waitcnt lgkmcnt(4)" ::: "memory");
    SCHEDB();
    __builtin_amdgcn_s_setprio(1);
    MFMA_Q(fB0, 0, 0);
    __builtin_amdgcn_s_setprio(0);

    // ---- Q01: fBc ready ----
    asm volatile("s_waitcnt lgkmcnt(0)" ::: "memory");
    SCHEDB();
    __builtin_amdgcn_s_setprio(1);
    MFMA_Q(fBc, 0, 1);
    __builtin_amdgcn_s_setprio(0);

    // ---- reads: fA-2nd (8, reuse fA regs) ----
#pragma unroll
    for (int mf = 0; mf < 4; mf++)
#pragma unroll
      for (int kk = 0; kk < 2; kk++)
        fA[mf][kk] = *(const bf16x8*)(ac + ((aoff + (mf + 4) * 2048 + kk * 64) ^ fl));
    asm volatile("s_waitcnt lgkmcnt(0)" ::: "memory");
    SCHEDB();

    // ---- mid barrier: ALL waves' tile-t reads complete -> safe to overwrite ----
    SBAR();
    if (t + 2 < NT) {
      STAGE_B(t + 2, 0, bc);
      STAGE_B(t + 2, 1, bc);
      STAGE_A(t + 2, 0, ac);
    }
    __builtin_amdgcn_s_setprio(1);
    MFMA_Q(fBc, 1, 1);
    MFMA_Q(fB0, 1, 0);
    __builtin_amdgcn_s_setprio(0);

    // ---- boundary: keep 6 newest (t+2 mid-stages); everything for t+1 resident ----
    if (t + 2 < NT) {
      asm volatile("s_waitcnt vmcnt(6)" ::: "memory");
      SBAR();
    } else if (t + 1 < NT) {
      asm volatile("s_waitcnt vmcnt(0)" ::: "memory");
      SBAR();
    }
  }

#pragma unroll
  for (int mf = 0; mf < 8; mf++)
#pragma unroll
    for (int nf = 0; nf < 4; nf++)
#pragma unroll
      for (int r = 0; r < 4; r++) {
        size_t row = (size_t)row0 + wm * 128 + mf * 16 + l4 * 4 + r;
        size_t col = (size_t)col0 + wn * 64 + nf * 16 + l15;
        store_c(C, row * (size_t)ldc + col, acc[mf][nf][r]);
      }
#undef STAGE_A
#undef STAGE_B
#undef MFMA_Q
}

// ---------------- 256x128 GEMM, 2-barrier/K-tile (gemm1 K/V columns; round-8 proven) ----------------
__global__ __launch_bounds__(512, 2) void gemm_bn128(const u16* __restrict__ A, const u16* __restrict__ B,
                                                     u16* __restrict__ C, int M, int N, int K, int ldc) {
  __shared__ __align__(16) u16 lds[49152];  // 96 KiB
  char* LB = (char*)lds;
  const int tid = threadIdx.x;
  const int w = tid >> 6, lane = tid & 63;
  const int l15 = lane & 15, l4 = lane >> 4;
  const int wm = w >> 2, wn = w & 3;

  int nwg = gridDim.x;
  int q = nwg >> 3, rr = nwg & 7;
  int xcd = blockIdx.x & 7, idx = blockIdx.x >> 3;
  int sw = (xcd < rr ? xcd * (q + 1) : rr * (q + 1) + (xcd - rr) * q) + idx;
  int gxn = N >> 7;
  int by = sw / gxn, bx = sw - by * gxn;
  const int row0 = by << 8, col0 = bx << 7;
  const int NT = K >> 6;

  const int srow = w * 8 + (lane >> 3);
  const int sc16 = (lane & 7) ^ ((lane >> 3) & 7);
  const u16* gA = A + (size_t)(row0 + srow) * K + sc16 * 8;
  const u16* gB = B + (size_t)(col0 + srow) * K + sc16 * 8;

  const int fl = (l15 & 7) << 4;
  const int aoff = (wm * 128 + l15) * 128 + l4 * 16;
  const int boff = (wn * 32 + l15) * 128 + l4 * 16;

  f32x4 acc[8][2] = {};
  bf16x8 fA[4][2], fB[2][2];

#define STAGE_A(kt, h, base)                                                      \
  {                                                                               \
    const u16* g_ = gA + (size_t)((h)*128) * K + (size_t)(kt)*64;                 \
    gload_lds16(g_, (base) + (h)*16384 + w * 1024);                               \
    gload_lds16(g_ + (size_t)64 * K, (base) + (h)*16384 + 8192 + w * 1024);       \
  }
#define STAGE_B(kt, base)                                                         \
  {                                                                               \
    const u16* g_ = gB + (size_t)(kt)*64;                                         \
    gload_lds16(g_, (base) + w * 1024);                                           \
    gload_lds16(g_ + (size_t)64 * K, (base) + 8192 + w * 1024);                   \
  }

  STAGE_A(0, 0, LB);
  STAGE_A(0, 1, LB);
  STAGE_B(0, LB + 65536);
  STAGE_A(1, 0, LB + 32768);
  STAGE_B(1, LB + 65536 + 16384);
  asm volatile("s_waitcnt vmcnt(4)" ::: "memory");
  SBAR();

  for (int t = 0; t < NT; ++t) {
    char* ac = LB + (t & 1) * 32768;
    char* bc = LB + 65536 + (t & 1) * 16384;
    char* an = LB + ((t + 1) & 1) * 32768;

    if (t + 1 < NT) STAGE_A(t + 1, 1, an);

    // ---- reads: fA-1st (8) + fB (4) ----
#pragma unroll
    for (int mf = 0; mf < 4; mf++)
#pragma unroll
      for (int kk = 0; kk < 2; kk++)
        fA[mf][kk] = *(const bf16x8*)(ac + ((aoff + mf * 2048 + kk * 64) ^ fl));
#pragma unroll
    for (int nf = 0; nf < 2; nf++)
#pragma unroll
      for (int kk = 0; kk < 2; kk++)
        fB[nf][kk] = *(const bf16x8*)(bc + ((boff + nf * 2048 + kk * 64) ^ fl));
    SCHEDB();
    asm volatile("s_waitcnt lgkmcnt(0)" ::: "memory");
    SCHEDB();
    __builtin_amdgcn_s_setprio(1);
#pragma unroll
    for (int kk = 0; kk < 2; kk++)
#pragma unroll
      for (int mf = 0; mf < 4; mf++)
#pragma unroll
        for (int nf = 0; nf < 2; nf++)
          acc[mf][nf] = __builtin_amdgcn_mfma_f32_16x16x32_bf16(fA[mf][kk], fB[nf][kk], acc[mf][nf], 0, 0, 0);
    __builtin_amdgcn_s_setprio(0);

    // ---- reads: fA-2nd (8) ----
#pragma unroll
    for (int mf = 0; mf < 4; mf++)
#pragma unroll
      for (int kk = 0; kk < 2; kk++)
        fA[mf][kk] = *(const bf16x8*)(ac + ((aoff + (mf + 4) * 2048 + kk * 64) ^ fl));
    asm volatile("s_waitcnt lgkmcnt(0)" ::: "memory");
    SCHEDB();

    SBAR();  // all reads done
    if (t + 2 < NT) {
      STAGE_A(t + 2, 0, ac);
      STAGE_B(t + 2, bc);
    }
    __builtin_amdgcn_s_setprio(1);
#pragma unroll
    for (int kk = 0; kk < 2; kk++)
#pragma unroll
      for (int mf = 0; mf < 4; mf++)
#pragma unroll
        for (int nf = 0; nf < 2; nf++)
          acc[mf + 4][nf] = __builtin_amdgcn_mfma_f32_16x16x32_bf16(fA[mf][kk], fB[nf][kk], acc[mf + 4][nf], 0, 0, 0);
    __builtin_amdgcn_s_setprio(0);

    if (t + 2 < NT) {
      asm volatile("s_waitcnt vmcnt(4)" ::: "memory");
      SBAR();
    } else if (t + 1 < NT) {
      asm volatile("s_waitcnt vmcnt(0)" ::: "memory");
      SBAR();
    }
  }

#pragma unroll
  for (int mf = 0; mf < 8; mf++)
#pragma unroll
    for (int nf = 0; nf < 2; nf++)
#pragma unroll
      for (int r = 0; r < 4; r++) {
        size_t row = (size_t)row0 + wm * 128 + mf * 16 + l4 * 4 + r;
        size_t col = (size_t)col0 + wn * 32 + nf * 16 + l15;
        C[row * (size_t)ldc + col] = f2bf(acc[mf][nf][r]);
      }
#undef STAGE_A
#undef STAGE_B
}

// ---------------- causal GQA flash attention v3 (round-7 proven) ----------------
__global__ __launch_bounds__(256, 2) void attn_fwd(const u16* __restrict__ qkv,
                                                   const u16* __restrict__ vtg,
                                                   u16* __restrict__ out) {
  constexpr int S = 2048, F = 6144, E = 4096;
  __shared__ __align__(16) u16 Kt[2 * 8192];
  __shared__ __align__(16) u16 Vt[2 * 8192];

  const int tid = threadIdx.x;
  const int w = tid >> 6, lane = tid & 63;
  const int l31 = lane & 31, hi = lane >> 5;
  const int pair = blockIdx.x;  // 0..7
  const int b = blockIdx.y >> 5, h = blockIdx.y & 31, kvh = h >> 2;
  const size_t rowB = (size_t)b * S;
  const float sc = 0.08838834764831845f * 1.4426950408889634f;  // 1/sqrt(128)*log2(e)
  const int sgn = tid >> 4, sgc = tid & 15;
  const size_t vtb = (size_t)(b * 8 + kvh) * 32 * 8192;

  auto stage = [&](int j, int buf) {
    char* kd = ((char*)Kt) + buf * 16384 + w * 1024;
    char* vd = ((char*)Vt) + buf * 16384 + w * 1024;
    const u16* vs = vtg + vtb + (size_t)j * 8192 + tid * 8;
#pragma unroll
    for (int p = 0; p < 4; p++) {
      int n = p * 16 + sgn;
      const u16* g = qkv + (rowB + j * 64 + n) * F + 4096 + kvh * 128 + (sgc ^ (n & 7)) * 8;
      gload_lds16(g, kd + p * 4096);
      gload_lds16(vs + p * 2048, vd + p * 4096);
    }
  };

  for (int half = 0; half < 2; ++half) {
    const int t = half ? 15 - pair : pair;
    const int nt = 2 * t + 2;
    const int r0 = t * 128;
    const int qg = r0 + w * 32 + l31;

    bf16x8 qf[8];
    {
      const u16* qp = qkv + (rowB + qg) * F + h * 128 + hi * 8;
#pragma unroll
      for (int ds = 0; ds < 8; ds++) qf[ds] = *reinterpret_cast<const bf16x8*>(qp + ds * 16);
    }

    f32x16 acco[4] = {};
    float m = -1e30f, l = 0.f;

    stage(0, 0);
    __syncthreads();

    for (int j = 0; j < nt; ++j) {
      const int cur = j & 1;
      if (j + 1 < nt) stage(j + 1, cur ^ 1);

      const char* kbase = ((const char*)Kt) + cur * 16384;
      f32x16 s0 = {}, s1 = {};
      __builtin_amdgcn_s_setprio(1);
#pragma unroll
      for (int ds = 0; ds < 8; ds++) {
        int ch = ((2 * ds + hi) ^ (l31 & 7)) << 4;
        bf16x8 k0 = *reinterpret_cast<const bf16x8*>(kbase + l31 * 256 + ch);
        bf16x8 k1 = *reinterpret_cast<const bf16x8*>(kbase + (32 + l31) * 256 + ch);
        s0 = __builtin_amdgcn_mfma_f32_32x32x16_bf16(k0, qf[ds], s0, 0, 0, 0);
        s1 = __builtin_amdgcn_mfma_f32_32x32x16_bf16(k1, qf[ds], s1, 0, 0, 0);
      }
      __builtin_amdgcn_s_setprio(0);

      f32x16 px0, px1;
      if (j >= 2 * t) {
#pragma unroll
        for (int rg = 0; rg < 16; rg++) {
          int kv0 = j * 64 + (rg & 3) + 8 * (rg >> 2) + 4 * hi;
          px0[rg] = (kv0 > qg) ? -1e30f : s0[rg] * sc;
          px1[rg] = (kv0 + 32 > qg) ? -1e30f : s1[rg] * sc;
        }
      } else {
#pragma unroll
        for (int rg = 0; rg < 16; rg++) {
          px0[rg] = s0[rg] * sc;
          px1[rg] = s1[rg] * sc;
        }
      }

      float mt[8];
#pragma unroll
      for (int i = 0; i < 8; i++)
        mt[i] = fmaxf(fmaxf(px0[i], px0[i + 8]), fmaxf(px1[i], px1[i + 8]));
#pragma unroll
      for (int stp = 4; stp; stp >>= 1)
#pragma unroll
        for (int i = 0; i < stp; i++) mt[i] = fmaxf(mt[i], mt[i + stp]);
      float pm = fmaxf(mt[0], __shfl_xor(mt[0], 32));

      if (__any(pm > m + 8.0f)) {
        float mn = fmaxf(m, pm);
        float fr = exp2f(m - mn);
        m = mn;
        l *= fr;
#pragma unroll
        for (int rg = 0; rg < 16; rg++) {
          int qrow = (rg & 3) + 8 * (rg >> 2) + 4 * hi;
          float frq = __builtin_bit_cast(
              float, __builtin_amdgcn_ds_bpermute(qrow << 2, __builtin_bit_cast(int, fr)));
          acco[0][rg] *= frq;
          acco[1][rg] *= frq;
          acco[2][rg] *= frq;
          acco[3][rg] *= frq;
        }
      }

#pragma unroll
      for (int rg = 0; rg < 16; rg++) {
        px0[rg] = exp2f(px0[rg] - m);
        px1[rg] = exp2f(px1[rg] - m);
      }
      float at[8];
#pragma unroll
      for (int i = 0; i < 8; i++)
        at[i] = (px0[i] + px0[i + 8]) + (px1[i] + px1[i + 8]);
#pragma unroll
      for (int stp = 4; stp; stp >>= 1)
#pragma unroll
        for (int i = 0; i < stp; i++) at[i] += at[i + stp];
      l += at[0] + __shfl_xor(at[0], 32);

      const char* vbase = ((const char*)Vt) + cur * 16384;
      __builtin_amdgcn_s_setprio(1);
#define PV_STEP(PH, SS)                                                               \
  {                                                                                   \
    uint32_t X0 = cvtpk(PH[((SS)&1) * 8 + 0], PH[((SS)&1) * 8 + 1]);                  \
    uint32_t Y0 = cvtpk(PH[((SS)&1) * 8 + 4], PH[((SS)&1) * 8 + 5]);                  \
    uint32_t X1 = cvtpk(PH[((SS)&1) * 8 + 2], PH[((SS)&1) * 8 + 3]);                  \
    uint32_t Y1 = cvtpk(PH[((SS)&1) * 8 + 6], PH[((SS)&1) * 8 + 7]);                  \
    plswap(X0, Y0);                                                                   \
    plswap(X1, Y1);                                                                   \
    u32x4 pw = {X0, X1, Y0, Y1};                                                      \
    bf16x8 pa = __builtin_bit_cast(bf16x8, pw);                                       \
    _Pragma("unroll") for (int df = 0; df < 4; df++) {                                \
      bf16x8 vf = *reinterpret_cast<const bf16x8*>(                                   \
          vbase + (32 * df + l31) * 128 + (((2 * (SS) + hi) ^ (l31 & 7)) << 4));      \
      acco[df] = __builtin_amdgcn_mfma_f32_32x32x16_bf16(pa, vf, acco[df], 0, 0, 0);  \
    }                                                                                 \
  }
      PV_STEP(px0, 0)
      PV_STEP(px0, 1)
      PV_STEP(px1, 2)
      PV_STEP(px1, 3)
#undef PV_STEP
      __builtin_amdgcn_s_setprio(0);

      __syncthreads();
    }

    float linv = 1.f / l;
#pragma unroll
    for (int rg = 0; rg < 16; rg++) {
      int qrow = (rg & 3) + 8 * (rg >> 2) + 4 * hi;
      float lv = __builtin_bit_cast(
          float, __builtin_amdgcn_ds_bpermute(qrow << 2, __builtin_bit_cast(int, linv)));
      size_t row = rowB + r0 + w * 32 + qrow;
      u16* op = out + row * E + h * 128 + l31;
#pragma unroll
      for (int df = 0; df < 4; df++) op[df * 32] = f2bf(acco[df][rg] * lv);
    }
  }
}

extern "C" void kernel_launch(void* const* d_in, const int* in_sizes, int n_in,
                              void* d_out, int out_size, void* d_ws, size_t ws_size,
                              hipStream_t stream) {
  const float* x = (const float*)d_in[0];
  const float* w_in = (const float*)d_in[1];
  const float* w_out = (const float*)d_in[2];
  float* out = (float*)d_out;
  char* ws = (char*)d_ws;

  u16* xb = (u16*)(ws);                                   // 33,554,432 B (reused as attn out)
  u16* wib = (u16*)(ws + 33554432ull);                    // 50,331,648 B (reused as V^T images)
  u16* wob = (u16*)(ws + 83886080ull);                    // 33,554,432 B
  u16* qkvb = (u16*)(ws + 117440512ull);                  // 50,331,648 B
  float* ct = (float*)(ws + 167772160ull);                // 524,288 B
  float* st = ct + 2048 * 64;                             // 524,288 B
  u16* attnb = xb;
  u16* vtg = wib;

  prep_all<<<29184, 256, 0, stream>>>(x, w_in, w_out, xb, wib, wob, ct, st);
  gemm256<u16><<<256, 512, 0, stream>>>(xb, wib, qkvb, 4096, 4096, 4096, 6144);
  gemm_bn128<<<256, 512, 0, stream>>>(xb, wib + (size_t)4096 * 4096, qkvb + 4096, 4096, 2048, 4096, 6144);
  rope_and_vt<<<5632, 256, 0, stream>>>(qkvb, ct, st, vtg);
  attn_fwd<<<dim3(8, 64), 256, 0, stream>>>(qkvb, vtg, attnb);
  gemm256<float><<<256, 512, 0, stream>>>(attnb, wob, out, 4096, 4096, 4096, 4096);
}